// Round 2
// baseline (911.477 us; speedup 1.0000x reference)
//
#include <hip/hip_runtime.h>

typedef __bf16 bf16;
typedef __bf16 bf16x8 __attribute__((ext_vector_type(8)));
typedef __bf16 bf16x4 __attribute__((ext_vector_type(4)));
typedef float  f32x4  __attribute__((ext_vector_type(4)));

// LDS layout (elements of bf16). All row strides are multiples of 8 elems
// (16 B) so ds_read_b128 / ds_write_b64 stay aligned.
#define LDA   264                      // padded row stride for X/Q/O and K tiles
#define LDV   72                       // Vt row stride (dim-major V), 144 B
#define LDP   72                       // P row stride, 144 B
#define OFF_K (64 * LDA)
#define OFF_V (128 * LDA)
#define OFF_P (128 * LDA + 256 * LDV)
#define LDS_ELEMS (OFF_P + 8 * 32 * LDP)   // 70656 elems = 141312 B (<160 KiB)

static __device__ __forceinline__ f32x4 mfma16(bf16x8 a, bf16x8 b, f32x4 c) {
  return __builtin_amdgcn_mfma_f32_16x16x32_bf16(a, b, c, 0, 0, 0);
}

// Prep: f32 weights -> transposed bf16 (B-frag wants W^T[n][k], k-contiguous);
// expand relative-position bias into biasT[h][key_col][query_row] (f32) so the
// score accumulator inits with one dwordx4 per 16x16 tile.
__global__ void prep_kernel(const float* __restrict__ Wq, const float* __restrict__ Wkv,
                            const float* __restrict__ Wp, const float* __restrict__ btab,
                            bf16* __restrict__ WqT, bf16* __restrict__ WkvT,
                            bf16* __restrict__ WpT, float* __restrict__ biasT) {
  int idx = blockIdx.x * 512 + threadIdx.x;       // 0 .. 294911
  if (idx < 65536) {
    int n = idx >> 8, k = idx & 255;
    WqT[idx] = (bf16)Wq[k * 256 + n];
  } else if (idx < 196608) {
    int j = idx - 65536, n = j >> 8, k = j & 255;
    WkvT[j] = (bf16)Wkv[k * 512 + n];
  } else if (idx < 262144) {
    int j = idx - 196608, n = j >> 8, k = j & 255;
    WpT[j] = (bf16)Wp[k * 256 + n];
  } else {
    int j = idx - 262144;                          // j = h*4096 + ck*64 + rq
    int h = j >> 12, ck = (j >> 6) & 63, rq = j & 63;
    int rel = ((rq >> 3) - (ck >> 3) + 7) * 15 + ((rq & 7) - (ck & 7) + 7);
    biasT[j] = btab[rel * 8 + h];
  }
}

// One workgroup = one 64-token window. 8 waves; wave w owns column slice
// [32w,32w+32) of every projection = head w for the attention stage.
__global__ __launch_bounds__(512, 2) void fused_kernel(
    const float* __restrict__ Xq_g, const float* __restrict__ Xs_g,
    const float* __restrict__ bq,  const float* __restrict__ bkv,
    const float* __restrict__ bp,
    const bf16* __restrict__ WqT, const bf16* __restrict__ WkvT,
    const bf16* __restrict__ WpT, const float* __restrict__ biasT,
    float* __restrict__ out) {
  __shared__ __attribute__((aligned(16))) bf16 sm[LDS_ELEMS];
  const int tid  = (int)threadIdx.x;
  const int w    = tid >> 6;        // wave id 0..7
  const int lane = tid & 63;
  const int c    = lane & 15;       // MFMA col / A-row lane
  const int q    = lane >> 4;       // MFMA quad
  bf16* A_ = sm;                    // [64][264]  X, then Q, then O
  bf16* K_ = sm + OFF_K;            // [64][264]  K (token-major)
  bf16* V_ = sm + OFF_V;            // [256][72]  V dim-major (Vt[dim][tok])
  bf16* P_ = sm + OFF_P + w * (32 * LDP);  // per-wave softmax scratch [32][72]
  const long long xoff = (long long)blockIdx.x * (64 * 256);

  // ---- stage 0: stage source tokens into A_ (f32 -> bf16, coalesced) ----
  {
    const float4* src = (const float4*)(Xs_g + xoff);
    #pragma unroll
    for (int i = 0; i < 8; ++i) {
      int chunk = tid + i * 512;                  // 0..4095 16B f32 chunks
      int row = chunk >> 6, col = (chunk & 63) << 2;
      float4 v = src[chunk];
      bf16x4 b4 = {(bf16)v.x, (bf16)v.y, (bf16)v.z, (bf16)v.w};
      *(bf16x4*)(A_ + row * LDA + col) = b4;      // 8 B aligned store
    }
  }
  __syncthreads();

  // ---- stage 1: KV = Xs @ Wkv + bkv ; wave w -> cols [64w,64w+64) ----
  {
    f32x4 acc[4][4];
    #pragma unroll
    for (int nt = 0; nt < 4; ++nt) {
      float bv = bkv[w * 64 + nt * 16 + c];
      #pragma unroll
      for (int mt = 0; mt < 4; ++mt) acc[mt][nt] = (f32x4){bv, bv, bv, bv};
    }
    #pragma unroll
    for (int kt = 0; kt < 8; ++kt) {
      bf16x8 af[4], bw[4];
      #pragma unroll
      for (int mt = 0; mt < 4; ++mt)
        af[mt] = *(const bf16x8*)(A_ + (mt * 16 + c) * LDA + kt * 32 + q * 8);
      #pragma unroll
      for (int nt = 0; nt < 4; ++nt)
        bw[nt] = *(const bf16x8*)(WkvT + (w * 64 + nt * 16 + c) * 256 + kt * 32 + q * 8);
      #pragma unroll
      for (int mt = 0; mt < 4; ++mt)
        #pragma unroll
        for (int nt = 0; nt < 4; ++nt)
          acc[mt][nt] = mfma16(af[mt], bw[nt], acc[mt][nt]);
    }
    if (w < 4) {   // K half (cols 0..255 of KV): token-major
      #pragma unroll
      for (int mt = 0; mt < 4; ++mt)
        #pragma unroll
        for (int nt = 0; nt < 4; ++nt)
          #pragma unroll
          for (int r = 0; r < 4; ++r)
            K_[(mt * 16 + q * 4 + r) * LDA + w * 64 + nt * 16 + c] = (bf16)acc[mt][nt][r];
    } else {       // V half (cols 256..511): dim-major for P@V B-frags
      #pragma unroll
      for (int mt = 0; mt < 4; ++mt)
        #pragma unroll
        for (int nt = 0; nt < 4; ++nt)
          #pragma unroll
          for (int r = 0; r < 4; ++r)
            V_[((w - 4) * 64 + nt * 16 + c) * LDV + mt * 16 + q * 4 + r] = (bf16)acc[mt][nt][r];
    }
  }
  __syncthreads();   // Xs reads done; K/V visible later

  // ---- stage 0b: stage query tokens into A_ ----
  {
    const float4* src = (const float4*)(Xq_g + xoff);
    #pragma unroll
    for (int i = 0; i < 8; ++i) {
      int chunk = tid + i * 512;
      int row = chunk >> 6, col = (chunk & 63) << 2;
      float4 v = src[chunk];
      bf16x4 b4 = {(bf16)v.x, (bf16)v.y, (bf16)v.z, (bf16)v.w};
      *(bf16x4*)(A_ + row * LDA + col) = b4;
    }
  }
  __syncthreads();

  // ---- stage 2: Q = (Xq @ Wq + bq) * scale ; wave w -> cols [32w,32w+32) ----
  f32x4 qacc[4][2];
  {
    #pragma unroll
    for (int nt = 0; nt < 2; ++nt) {
      float bv = bq[w * 32 + nt * 16 + c];
      #pragma unroll
      for (int mt = 0; mt < 4; ++mt) qacc[mt][nt] = (f32x4){bv, bv, bv, bv};
    }
    #pragma unroll
    for (int kt = 0; kt < 8; ++kt) {
      bf16x8 af[4], bw[2];
      #pragma unroll
      for (int mt = 0; mt < 4; ++mt)
        af[mt] = *(const bf16x8*)(A_ + (mt * 16 + c) * LDA + kt * 32 + q * 8);
      #pragma unroll
      for (int nt = 0; nt < 2; ++nt)
        bw[nt] = *(const bf16x8*)(WqT + (w * 32 + nt * 16 + c) * 256 + kt * 32 + q * 8);
      #pragma unroll
      for (int mt = 0; mt < 4; ++mt)
        #pragma unroll
        for (int nt = 0; nt < 2; ++nt)
          qacc[mt][nt] = mfma16(af[mt], bw[nt], qacc[mt][nt]);
    }
  }
  __syncthreads();   // all waves done reading Xq before Q overwrites A_
  {
    const float scale = 0.17677669529663687f;   // 1/sqrt(32)
    #pragma unroll
    for (int mt = 0; mt < 4; ++mt)
      #pragma unroll
      for (int nt = 0; nt < 2; ++nt)
        #pragma unroll
        for (int r = 0; r < 4; ++r)
          A_[(mt * 16 + q * 4 + r) * LDA + w * 32 + nt * 16 + c] = (bf16)(qacc[mt][nt][r] * scale);
  }
  // Q cols [32w,32w+32) are wave-private: no barrier needed before reading back.

  // ---- stage 3: attention, head h == w ----
  bf16x8 aq[4];
  #pragma unroll
  for (int mt = 0; mt < 4; ++mt)
    aq[mt] = *(const bf16x8*)(A_ + (mt * 16 + c) * LDA + w * 32 + q * 8);

  #pragma unroll
  for (int p = 0; p < 2; ++p) {          // two passes of 32 query rows
    f32x4 s[2][4];
    #pragma unroll
    for (int mt = 0; mt < 2; ++mt)
      #pragma unroll
      for (int nt = 0; nt < 4; ++nt)     // init with relative-position bias
        s[mt][nt] = *(const f32x4*)(biasT + (w * 64 + nt * 16 + c) * 64 + p * 32 + mt * 16 + q * 4);
    bf16x8 bk[4];
    #pragma unroll
    for (int nt = 0; nt < 4; ++nt)
      bk[nt] = *(const bf16x8*)(K_ + (nt * 16 + c) * LDA + w * 32 + q * 8);
    #pragma unroll
    for (int mt = 0; mt < 2; ++mt)
      #pragma unroll
      for (int nt = 0; nt < 4; ++nt)
        s[mt][nt] = mfma16(aq[p * 2 + mt], bk[nt], s[mt][nt]);

    // softmax over keys: 4 in-lane tiles + 16-lane butterfly within quad
    float rl[2][4];
    #pragma unroll
    for (int mt = 0; mt < 2; ++mt) {
      #pragma unroll
      for (int r = 0; r < 4; ++r) {
        float m0 = fmaxf(fmaxf(s[mt][0][r], s[mt][1][r]), fmaxf(s[mt][2][r], s[mt][3][r]));
        m0 = fmaxf(m0, __shfl_xor(m0, 1));
        m0 = fmaxf(m0, __shfl_xor(m0, 2));
        m0 = fmaxf(m0, __shfl_xor(m0, 4));
        m0 = fmaxf(m0, __shfl_xor(m0, 8));
        const float L2E = 1.4426950408889634f;
        float t0 = exp2f((s[mt][0][r] - m0) * L2E);
        float t1 = exp2f((s[mt][1][r] - m0) * L2E);
        float t2 = exp2f((s[mt][2][r] - m0) * L2E);
        float t3 = exp2f((s[mt][3][r] - m0) * L2E);
        s[mt][0][r] = t0; s[mt][1][r] = t1; s[mt][2][r] = t2; s[mt][3][r] = t3;
        float sum = (t0 + t1) + (t2 + t3);
        sum += __shfl_xor(sum, 1);
        sum += __shfl_xor(sum, 2);
        sum += __shfl_xor(sum, 4);
        sum += __shfl_xor(sum, 8);
        rl[mt][r] = __builtin_amdgcn_rcpf(sum);   // normalize O later; sum >= 1
      }
    }
    // P (unnormalized) -> wave-private LDS, row-major for A-frags
    #pragma unroll
    for (int mt = 0; mt < 2; ++mt)
      #pragma unroll
      for (int nt = 0; nt < 4; ++nt)
        #pragma unroll
        for (int r = 0; r < 4; ++r)
          P_[(mt * 16 + q * 4 + r) * LDP + nt * 16 + c] = (bf16)s[mt][nt][r];

    // O = P @ V_head ; normalize rows by 1/l ; write into A_ (wave-private cols)
    bf16x8 bv2[2][2];
    #pragma unroll
    for (int nt = 0; nt < 2; ++nt)
      #pragma unroll
      for (int t = 0; t < 2; ++t)
        bv2[nt][t] = *(const bf16x8*)(V_ + (w * 32 + nt * 16 + c) * LDV + t * 32 + q * 8);
    #pragma unroll
    for (int mt = 0; mt < 2; ++mt) {
      bf16x8 ap0 = *(const bf16x8*)(P_ + (mt * 16 + c) * LDP + q * 8);
      bf16x8 ap1 = *(const bf16x8*)(P_ + (mt * 16 + c) * LDP + 32 + q * 8);
      #pragma unroll
      for (int nt = 0; nt < 2; ++nt) {
        f32x4 o = (f32x4){0.f, 0.f, 0.f, 0.f};
        o = mfma16(ap0, bv2[nt][0], o);
        o = mfma16(ap1, bv2[nt][1], o);
        #pragma unroll
        for (int r = 0; r < 4; ++r)
          A_[(p * 32 + mt * 16 + q * 4 + r) * LDA + w * 32 + nt * 16 + c] =
              (bf16)(o[r] * rl[mt][r]);
      }
    }
  }
  __syncthreads();   // all O written before projection reads full rows

  // ---- stage 4: out = O @ Wp + bp ; wave w -> cols [32w,32w+32) ----
  {
    f32x4 acc[4][2];
    #pragma unroll
    for (int nt = 0; nt < 2; ++nt) {
      float bv = bp[w * 32 + nt * 16 + c];
      #pragma unroll
      for (int mt = 0; mt < 4; ++mt) acc[mt][nt] = (f32x4){bv, bv, bv, bv};
    }
    #pragma unroll
    for (int kt = 0; kt < 8; ++kt) {
      bf16x8 af[4], bw[2];
      #pragma unroll
      for (int mt = 0; mt < 4; ++mt)
        af[mt] = *(const bf16x8*)(A_ + (mt * 16 + c) * LDA + kt * 32 + q * 8);
      #pragma unroll
      for (int nt = 0; nt < 2; ++nt)
        bw[nt] = *(const bf16x8*)(WpT + (w * 32 + nt * 16 + c) * 256 + kt * 32 + q * 8);
      #pragma unroll
      for (int mt = 0; mt < 4; ++mt)
        #pragma unroll
        for (int nt = 0; nt < 2; ++nt)
          acc[mt][nt] = mfma16(af[mt], bw[nt], acc[mt][nt]);
    }
    float* dst = out + xoff;
    #pragma unroll
    for (int mt = 0; mt < 4; ++mt)
      #pragma unroll
      for (int nt = 0; nt < 2; ++nt)
        #pragma unroll
        for (int r = 0; r < 4; ++r)
          dst[(mt * 16 + q * 4 + r) * 256 + w * 32 + nt * 16 + c] = acc[mt][nt][r];
  }
}

extern "C" void kernel_launch(void* const* d_in, const int* in_sizes, int n_in,
                              void* d_out, int out_size, void* d_ws, size_t ws_size,
                              hipStream_t stream) {
  const float* Xq   = (const float*)d_in[0];
  const float* Xs   = (const float*)d_in[1];
  const float* Wq   = (const float*)d_in[2];
  const float* bq   = (const float*)d_in[3];
  const float* Wkv  = (const float*)d_in[4];
  const float* bkv  = (const float*)d_in[5];
  const float* btab = (const float*)d_in[6];
  const float* Wp   = (const float*)d_in[7];
  const float* bp   = (const float*)d_in[8];
  float* out = (float*)d_out;

  char* ws = (char*)d_ws;
  bf16*  WqT   = (bf16*)(ws);                 // 256x256 bf16 = 131072 B
  bf16*  WkvT  = (bf16*)(ws + 131072);        // 512x256 bf16 = 262144 B
  bf16*  WpT   = (bf16*)(ws + 393216);        // 256x256 bf16 = 131072 B
  float* biasT = (float*)(ws + 524288);       // 8x64x64 f32  = 131072 B

  const int Bw = in_sizes[0] / (64 * 256);    // number of windows (4096)

  prep_kernel<<<dim3(576), dim3(512), 0, stream>>>(Wq, Wkv, Wp, btab,
                                                   WqT, WkvT, WpT, biasT);
  fused_kernel<<<dim3(Bw), dim3(512), 0, stream>>>(Xq, Xs, bq, bkv, bp,
                                                   WqT, WkvT, WpT, biasT, out);
}